// Round 2
// baseline (19908.134 us; speedup 1.0000x reference)
//
#include <hip/hip_runtime.h>
#include <hip/hip_bf16.h>

#define B 64
#define T 256
#define IN 512
#define H 1024
#define L 6

#define NBLK 192          // 6 layers * 32 col tiles
#define TPB 512           // 8 waves
#define NCOL 32           // output cols per block
#define TILES_PER_L 32
#define WSTRIDE (IN + H + 8)                 // 1544 bf16 (pad 8 -> 2-way B reads)
#define SMEM_W_BYTES (NCOL * WSTRIDE * 2)    // 98816
#define SMEM_A_BYTES (64 * 512)              // 32768: 64 rows x 256 bf16 (xor-swizzled)
#define SMEM_BYTES (SMEM_W_BYTES + SMEM_A_BYTES)  // 131584 <= 160K

typedef __bf16 bf16x8 __attribute__((ext_vector_type(8)));
typedef __bf16 bf16x4 __attribute__((ext_vector_type(4)));
typedef float f32x4 __attribute__((ext_vector_type(4)));

// ---------------------------------------------------------------------------
// prep: x [B,T,I] fp32 -> xbf [T,B,I] bf16 ; h0 fp32 -> hb0 bf16
// ---------------------------------------------------------------------------
__global__ void prep_kernel(const float* __restrict__ x,
                            const float* __restrict__ h0,
                            __bf16* __restrict__ xbf,
                            __bf16* __restrict__ hb0) {
    const int N4x = B * T * (IN / 4);
    const int N4h = L * B * (H / 4);
    int stride = gridDim.x * blockDim.x;
    for (int u = blockIdx.x * blockDim.x + threadIdx.x; u < N4x + N4h; u += stride) {
        if (u < N4x) {
            int b = u / (T * (IN / 4));
            int r = u % (T * (IN / 4));
            int t = r / (IN / 4), c4 = r % (IN / 4);
            float4 v = reinterpret_cast<const float4*>(x)[u];
            bf16x4 o = {(__bf16)v.x, (__bf16)v.y, (__bf16)v.z, (__bf16)v.w};
            *reinterpret_cast<bf16x4*>(xbf + ((size_t)t * B + b) * IN + c4 * 4) = o;
        } else {
            int j = u - N4x;
            float4 v = reinterpret_cast<const float4*>(h0)[j];
            bf16x4 o = {(__bf16)v.x, (__bf16)v.y, (__bf16)v.z, (__bf16)v.w};
            *reinterpret_cast<bf16x4*>(hb0 + (size_t)j * 4) = o;
        }
    }
}

// ---------------------------------------------------------------------------
// persistent per-(layer, col-tile) kernel. 1 block/CU (LDS-bound), 8 waves.
// Weights resident in LDS for all 256 steps; per-layer atomic barrier.
// ---------------------------------------------------------------------------
__global__ __launch_bounds__(TPB)
void rnn_kernel(const __bf16* __restrict__ xbf,   // [T][B][IN]
                const float*  __restrict__ wih,   // [L][H][IN] fp32
                const float*  __restrict__ whh,   // [L][H][H]  fp32
                const float*  __restrict__ bih,
                const float*  __restrict__ bhh,
                __bf16* __restrict__ hb0,         // [L][B][H]
                __bf16* __restrict__ hb1,
                float*  __restrict__ out,
                unsigned* __restrict__ ctrs) {
    extern __shared__ char smem[];
    __bf16* Wlds = (__bf16*)smem;
    char*   Abase = smem + SMEM_W_BYTES;

    const int l   = blockIdx.x / TILES_PER_L;
    const int n0  = (blockIdx.x % TILES_PER_L) * NCOL;
    const int tid = threadIdx.x;
    const int lane = tid & 63;
    const int wave = tid >> 6;
    const int mw = wave & 3;    // row-fragment (batch rows mw*16..)
    const int nw = wave >> 2;   // col-fragment (cols n0+nw*16..)
    const int lr = lane & 15;
    const int lk = lane >> 4;

    unsigned* ctr = ctrs + l * 16;   // 64B-separated per-layer counters

    // ---- one-time: weight slice fp32 -> bf16 -> LDS ------------------------
    for (int v = tid; v < NCOL * ((IN + H) / 4); v += TPB) {
        int gl = v / ((IN + H) / 4);
        int k  = (v % ((IN + H) / 4)) * 4;
        const float* src = (k < IN)
            ? wih + ((size_t)(l * H + n0 + gl)) * IN + k
            : whh + ((size_t)(l * H + n0 + gl)) * H + (k - IN);
        float4 f = *reinterpret_cast<const float4*>(src);
        bf16x4 o = {(__bf16)f.x, (__bf16)f.y, (__bf16)f.z, (__bf16)f.w};
        *reinterpret_cast<bf16x4*>(Wlds + (size_t)gl * WSTRIDE + k) = o;
    }

    const int g = n0 + nw * 16 + lr;           // output column (global)
    const float bv = bih[l * H + g] + bhh[l * H + g];
    const int arow  = mw * 16 + lr;            // A row this lane reads
    const int arxor = arow & 7;
    const int bgl   = nw * 16 + lr;            // W row (local col) this lane reads

    // stage one K=256 chunk of A (64 rows) into swizzled LDS
#define STAGE_CHUNK(SRC_BASE, ROWLEN, KOFF)                                     \
    {  _Pragma("unroll")                                                        \
       for (int j = 0; j < 4; ++j) {                                            \
           int s = tid + j * TPB;                                               \
           int row = s >> 5, c = s & 31;                                        \
           float4 v = *reinterpret_cast<const float4*>(                         \
               (SRC_BASE) + (size_t)row * (ROWLEN) + (KOFF) + c * 8);           \
           *reinterpret_cast<float4*>(Abase + (row << 9) +                      \
                                      ((c ^ (row & 7)) << 4)) = v;              \
       } }

    // 8 MFMAs over the staged chunk; KB = k-offset into Wlds row
#define MFMA_CHUNK(KB, ACCA, ACCB)                                              \
    {  _Pragma("unroll")                                                        \
       for (int kk = 0; kk < 8; ++kk) {                                         \
           int u = (kk << 2) + lk;                                              \
           bf16x8 af = *reinterpret_cast<const bf16x8*>(                        \
               Abase + (arow << 9) + ((u ^ arxor) << 4));                       \
           bf16x8 bfr = *reinterpret_cast<const bf16x8*>(                       \
               Wlds + (size_t)bgl * WSTRIDE + (KB) + (kk << 5) + (lk << 3));    \
           if (kk & 1) ACCB = __builtin_amdgcn_mfma_f32_16x16x32_bf16(          \
                                  af, bfr, ACCB, 0, 0, 0);                      \
           else        ACCA = __builtin_amdgcn_mfma_f32_16x16x32_bf16(          \
                                  af, bfr, ACCA, 0, 0, 0);                      \
       } }

    const f32x4 zero = {0.f, 0.f, 0.f, 0.f};
    f32x4 axA = zero, axB = zero;

    // x-projection for t=0 (also flushes the weight-fill via chunk barriers)
    {
        const __bf16* xb = xbf;  // t = 0
        #pragma unroll
        for (int ck = 0; ck < 2; ++ck) {
            __syncthreads();
            STAGE_CHUNK(xb, IN, ck * 256);
            __syncthreads();
            MFMA_CHUNK(ck * 256, axA, axB);
        }
    }

    for (int t = 0; t < T; ++t) {
        const __bf16* hcur = (t & 1) ? hb1 : hb0;
        __bf16*       hnxt = (t & 1) ? hb0 : hb1;

        if (t > 0) {  // wait until all 32 blocks of this layer wrote h_t
            if (tid == 0) {
                unsigned target = (unsigned)(TILES_PER_L * t);
                while (__hip_atomic_load(ctr, __ATOMIC_ACQUIRE,
                                         __HIP_MEMORY_SCOPE_AGENT) < target)
                    __builtin_amdgcn_s_sleep(1);
            }
            __syncthreads();
            __threadfence();
        }

        f32x4 aA = axA, aB = axB;
        const __bf16* hsrc = hcur + (size_t)l * B * H;
        #pragma unroll
        for (int ck = 0; ck < 4; ++ck) {
            __syncthreads();
            STAGE_CHUNK(hsrc, H, ck * 256);
            __syncthreads();
            MFMA_CHUNK(IN + ck * 256, aA, aB);
        }

        // epilogue: bias + leaky-relu, write h slice (+ outputs)
        #pragma unroll
        for (int j = 0; j < 4; ++j) {
            int b = mw * 16 + lk * 4 + j;
            float v = aA[j] + aB[j] + bv;
            v = (v >= 0.f) ? v : 0.01f * v;
            hnxt[((size_t)(l * B + b)) * H + g] = (__bf16)v;
            if (l == L - 1) out[((size_t)b * T + t) * H + g] = v;
            if (t == T - 1)
                out[(size_t)B * T * H + ((size_t)(l * B + b)) * H + g] = v;
        }

        __threadfence();       // release h writes to device scope
        __syncthreads();       // all waves done before signaling
        if (tid == 0)
            __hip_atomic_fetch_add(ctr, 1u, __ATOMIC_RELEASE,
                                   __HIP_MEMORY_SCOPE_AGENT);

        if (t + 1 < T) {       // overlap: x-projection for t+1 (no h dep)
            axA = zero; axB = zero;
            const __bf16* xb = xbf + (size_t)(t + 1) * B * IN;
            #pragma unroll
            for (int ck = 0; ck < 2; ++ck) {
                __syncthreads();
                STAGE_CHUNK(xb, IN, ck * 256);
                __syncthreads();
                MFMA_CHUNK(ck * 256, axA, axB);
            }
        }
    }
}

// ---------------------------------------------------------------------------
extern "C" void kernel_launch(void* const* d_in, const int* in_sizes, int n_in,
                              void* d_out, int out_size, void* d_ws, size_t ws_size,
                              hipStream_t stream) {
    const float* x   = (const float*)d_in[0];
    const float* h0  = (const float*)d_in[1];
    const float* wih = (const float*)d_in[2];
    const float* whh = (const float*)d_in[3];
    const float* bih = (const float*)d_in[4];
    const float* bhh = (const float*)d_in[5];
    float* out = (float*)d_out;

    char* ws = (char*)d_ws;
    __bf16* xbf = (__bf16*)ws;                               // 16 MB
    __bf16* hb0 = (__bf16*)(ws + (size_t)16777216);          // 768 KB
    __bf16* hb1 = (__bf16*)(ws + (size_t)16777216 + 786432); // 768 KB
    unsigned* ctrs = (unsigned*)(ws + (size_t)16777216 + 2 * 786432);

    hipMemsetAsync(ctrs, 0, L * 16 * sizeof(unsigned), stream);
    prep_kernel<<<2048, 256, 0, stream>>>(x, h0, xbf, hb0);

    static bool attr_done = []() {
        hipFuncSetAttribute((const void*)rnn_kernel,
                            hipFuncAttributeMaxDynamicSharedMemorySize,
                            SMEM_BYTES);
        return true;
    }();
    (void)attr_done;

    rnn_kernel<<<NBLK, TPB, SMEM_BYTES, stream>>>(
        xbf, wih, whh, bih, bhh, hb0, hb1, out, ctrs);
}

// Round 5
// 1718.164 us; speedup vs baseline: 11.5869x; 11.5869x over previous
//
#include <hip/hip_runtime.h>
#include <hip/hip_bf16.h>

#define B 64
#define T 256
#define IN 512
#define H 1024
#define L 6

#define NBLK 192          // 6 layers * 32 col tiles
#define TPB 512           // 8 waves
#define NCOL 32           // output cols per block
#define TILES_PER_L 32
#define WSTRIDE (IN + H + 8)                 // 1544 bf16 (pad -> 2-way B reads)
#define SMEM_W_BYTES (NCOL * WSTRIDE * 2)    // 98816
#define SMEM_A_BYTES (64 * 512)              // 32768: 64 rows x 256 bf16, swizzled
#define SMEM_BYTES (SMEM_W_BYTES + SMEM_A_BYTES)  // 131584 <= 160K -> 1 block/CU

typedef __bf16 bf16x8 __attribute__((ext_vector_type(8)));
typedef __bf16 bf16x4 __attribute__((ext_vector_type(4)));
typedef float f32x4 __attribute__((ext_vector_type(4)));

// ---------------------------------------------------------------------------
// prep: x [B,T,I] fp32 -> xbf [T,B,I] bf16 ; h0 fp32 -> hb0 bf16
// ---------------------------------------------------------------------------
__global__ void prep_kernel(const float* __restrict__ x,
                            const float* __restrict__ h0,
                            __bf16* __restrict__ xbf,
                            __bf16* __restrict__ hb0) {
    const int N4x = B * T * (IN / 4);
    const int N4h = L * B * (H / 4);
    int stride = gridDim.x * blockDim.x;
    for (int u = blockIdx.x * blockDim.x + threadIdx.x; u < N4x + N4h; u += stride) {
        if (u < N4x) {
            int b = u / (T * (IN / 4));
            int r = u % (T * (IN / 4));
            int t = r / (IN / 4), c4 = r % (IN / 4);
            float4 v = reinterpret_cast<const float4*>(x)[u];
            bf16x4 o = {(__bf16)v.x, (__bf16)v.y, (__bf16)v.z, (__bf16)v.w};
            *reinterpret_cast<bf16x4*>(xbf + ((size_t)t * B + b) * IN + c4 * 4) = o;
        } else {
            int j = u - N4x;
            float4 v = reinterpret_cast<const float4*>(h0)[j];
            bf16x4 o = {(__bf16)v.x, (__bf16)v.y, (__bf16)v.z, (__bf16)v.w};
            *reinterpret_cast<bf16x4*>(hb0 + (size_t)j * 4) = o;
        }
    }
}

// ---------------------------------------------------------------------------
// Persistent per-(layer, col-tile) kernel. 1 block/CU, 8 waves.
// Weights resident in LDS. h exchanged through the Infinity Cache (sc0 sc1
// bypass loads/stores) -> NO L2 writeback/invalidate instructions anywhere.
// ---------------------------------------------------------------------------
__global__ __launch_bounds__(TPB)
void rnn_kernel(const __bf16* __restrict__ xbf,   // [T][B][IN]
                const float*  __restrict__ wih,   // [L][H][IN] fp32
                const float*  __restrict__ whh,   // [L][H][H]  fp32
                const float*  __restrict__ bih,
                const float*  __restrict__ bhh,
                __bf16* __restrict__ hb0,         // [L][B][H]
                __bf16* __restrict__ hb1,
                float*  __restrict__ out,
                unsigned* __restrict__ ctrs) {
    extern __shared__ char smem[];
    __bf16* Wlds = (__bf16*)smem;
    char*   Abase = smem + SMEM_W_BYTES;

    const int l    = blockIdx.x / TILES_PER_L;
    const int n0   = (blockIdx.x % TILES_PER_L) * NCOL;
    const int tid  = threadIdx.x;
    const int lane = tid & 63;
    const int wave = tid >> 6;
    const int mw = wave & 3;    // batch-row fragment
    const int nw = wave >> 2;   // col fragment
    const int lr = lane & 15;
    const int lk = lane >> 4;

    unsigned* ctr = ctrs + l * 16;

    // ---- one-time: weight slice fp32 -> bf16 -> LDS ------------------------
    for (int v = tid; v < NCOL * ((IN + H) / 4); v += TPB) {
        int gl = v / ((IN + H) / 4);
        int k  = (v % ((IN + H) / 4)) * 4;
        const float* src = (k < IN)
            ? wih + ((size_t)(l * H + n0 + gl)) * IN + k
            : whh + ((size_t)(l * H + n0 + gl)) * H + (k - IN);
        float4 f = *reinterpret_cast<const float4*>(src);
        bf16x4 o = {(__bf16)f.x, (__bf16)f.y, (__bf16)f.z, (__bf16)f.w};
        *reinterpret_cast<bf16x4*>(Wlds + (size_t)gl * WSTRIDE + k) = o;
    }

    const int g = n0 + nw * 16 + lr;           // output column (global)
    const float bv = bih[l * H + g] + bhh[l * H + g];
    const int arow  = mw * 16 + lr;            // A row this lane reads
    const int arxor = arow & 7;
    const int bgl   = nw * 16 + lr;            // W local row this lane reads

    const int row0 = tid >> 5;                 // staging row (0..15)
    const int c0   = tid & 31;                 // staging 16B-column (0..31)
    char* wb = Abase + (row0 << 9) + (((c0 ^ (row0 & 7))) << 4);

    // cached staging for x chunks (K=256 each)
#define STAGE_X(SRC_BASE, KOFF)                                                 \
    {  _Pragma("unroll")                                                        \
       for (int j = 0; j < 4; ++j) {                                            \
           int row = row0 + 16 * j;                                             \
           float4 v = *reinterpret_cast<const float4*>(                         \
               (SRC_BASE) + (size_t)row * IN + (KOFF) + c0 * 8);                \
           *reinterpret_cast<float4*>(wb + (j << 13)) = v;                      \
       } }

#define MFMA_CHUNK(KB, ACCA, ACCB)                                              \
    {  _Pragma("unroll")                                                        \
       for (int kk = 0; kk < 8; ++kk) {                                         \
           int u = (kk << 2) + lk;                                              \
           bf16x8 af = *reinterpret_cast<const bf16x8*>(                        \
               Abase + (arow << 9) + ((u ^ arxor) << 4));                       \
           bf16x8 bfr = *reinterpret_cast<const bf16x8*>(                       \
               Wlds + (size_t)bgl * WSTRIDE + (KB) + (kk << 5) + (lk << 3));    \
           if (kk & 1) ACCB = __builtin_amdgcn_mfma_f32_16x16x32_bf16(          \
                                  af, bfr, ACCB, 0, 0, 0);                      \
           else        ACCA = __builtin_amdgcn_mfma_f32_16x16x32_bf16(          \
                                  af, bfr, ACCA, 0, 0, 0);                      \
       } }

#define VMWAIT(N) do { asm volatile("s_waitcnt vmcnt(" #N ")" ::: "memory");    \
                       __builtin_amdgcn_sched_barrier(0); } while (0)

    const f32x4 zero = {0.f, 0.f, 0.f, 0.f};
    f32x4 axA = zero, axB = zero;

    // x-projection for t=0 (leading sync also flushes the weight fill)
    {
        const __bf16* xb = xbf;
        #pragma unroll
        for (int ck = 0; ck < 2; ++ck) {
            __syncthreads();
            STAGE_X(xb, ck * 256);
            __syncthreads();
            MFMA_CHUNK(ck * 256, axA, axB);
        }
    }

    for (int t = 0; t < T; ++t) {
        const __bf16* hcur = (t & 1) ? hb1 : hb0;
        __bf16*       hnxt = (t & 1) ? hb0 : hb1;

        if (t > 0 && wave == 0) {   // wave0 polls (RELAXED: no cache maintenance)
            const unsigned target = (unsigned)(TILES_PER_L * t);
            while (__hip_atomic_load(ctr, __ATOMIC_RELAXED,
                                     __HIP_MEMORY_SCOPE_AGENT) < target)
                __builtin_amdgcn_s_sleep(1);
        }
        __syncthreads();   // release all waves; also: x-MFMA reads done

        // ---- issue ALL 16 h loads (bypass L1/L2 -> Infinity Cache) ---------
        // NOTE: "=&v" early-clobber is REQUIRED: outputs must not overlap the
        // address inputs, since later loads read addrs after earlier loads
        // write their dest regs (round-4 fault).
        const char* hsrc = (const char*)(hcur + (size_t)l * B * H);
        const char* ha0 = hsrc + (size_t)(row0 +  0) * 2048 + c0 * 16;
        const char* ha1 = hsrc + (size_t)(row0 + 16) * 2048 + c0 * 16;
        const char* ha2 = hsrc + (size_t)(row0 + 32) * 2048 + c0 * 16;
        const char* ha3 = hsrc + (size_t)(row0 + 48) * 2048 + c0 * 16;
        f32x4 q0,q1,q2,q3,q4,q5,q6,q7,q8,q9,q10,q11,q12,q13,q14,q15;
        asm volatile(
            "global_load_dwordx4 %[q0],  %[a0], off sc0 sc1\n\t"
            "global_load_dwordx4 %[q1],  %[a1], off sc0 sc1\n\t"
            "global_load_dwordx4 %[q2],  %[a2], off sc0 sc1\n\t"
            "global_load_dwordx4 %[q3],  %[a3], off sc0 sc1\n\t"
            "global_load_dwordx4 %[q4],  %[a0], off offset:512 sc0 sc1\n\t"
            "global_load_dwordx4 %[q5],  %[a1], off offset:512 sc0 sc1\n\t"
            "global_load_dwordx4 %[q6],  %[a2], off offset:512 sc0 sc1\n\t"
            "global_load_dwordx4 %[q7],  %[a3], off offset:512 sc0 sc1\n\t"
            "global_load_dwordx4 %[q8],  %[a0], off offset:1024 sc0 sc1\n\t"
            "global_load_dwordx4 %[q9],  %[a1], off offset:1024 sc0 sc1\n\t"
            "global_load_dwordx4 %[q10], %[a2], off offset:1024 sc0 sc1\n\t"
            "global_load_dwordx4 %[q11], %[a3], off offset:1024 sc0 sc1\n\t"
            "global_load_dwordx4 %[q12], %[a0], off offset:1536 sc0 sc1\n\t"
            "global_load_dwordx4 %[q13], %[a1], off offset:1536 sc0 sc1\n\t"
            "global_load_dwordx4 %[q14], %[a2], off offset:1536 sc0 sc1\n\t"
            "global_load_dwordx4 %[q15], %[a3], off offset:1536 sc0 sc1"
            : [q0]"=&v"(q0), [q1]"=&v"(q1), [q2]"=&v"(q2), [q3]"=&v"(q3),
              [q4]"=&v"(q4), [q5]"=&v"(q5), [q6]"=&v"(q6), [q7]"=&v"(q7),
              [q8]"=&v"(q8), [q9]"=&v"(q9), [q10]"=&v"(q10), [q11]"=&v"(q11),
              [q12]"=&v"(q12), [q13]"=&v"(q13), [q14]"=&v"(q14), [q15]"=&v"(q15)
            : [a0]"v"(ha0), [a1]"v"(ha1), [a2]"v"(ha2), [a3]"v"(ha3)
            : "memory");

        f32x4 aA = axA, aB = axB;

#define WRITE4(QA, QB, QC, QD)                                                  \
        *reinterpret_cast<f32x4*>(wb)         = QA;                             \
        *reinterpret_cast<f32x4*>(wb + 8192)  = QB;                             \
        *reinterpret_cast<f32x4*>(wb + 16384) = QC;                             \
        *reinterpret_cast<f32x4*>(wb + 24576) = QD;

        // chunk 0
        VMWAIT(12); WRITE4(q0, q1, q2, q3);
        __syncthreads(); MFMA_CHUNK(IN + 0 * 256, aA, aB);
        // chunk 1
        __syncthreads(); VMWAIT(8); WRITE4(q4, q5, q6, q7);
        __syncthreads(); MFMA_CHUNK(IN + 1 * 256, aA, aB);
        // chunk 2
        __syncthreads(); VMWAIT(4); WRITE4(q8, q9, q10, q11);
        __syncthreads(); MFMA_CHUNK(IN + 2 * 256, aA, aB);
        // chunk 3
        __syncthreads(); VMWAIT(0); WRITE4(q12, q13, q14, q15);
        __syncthreads(); MFMA_CHUNK(IN + 3 * 256, aA, aB);

        // ---- epilogue: bias + leaky relu; h via IF-coherent stores ---------
        {
            float vv[4];
            #pragma unroll
            for (int j = 0; j < 4; ++j) {
                float v = aA[j] + aB[j] + bv;
                vv[j] = (v >= 0.f) ? v : 0.01f * v;
            }
            union { __bf16 b; unsigned short u; } cv;
            uint32_t s0, s1, s2, s3;
            cv.b = (__bf16)vv[0]; s0 = cv.u;
            cv.b = (__bf16)vv[1]; s1 = cv.u;
            cv.b = (__bf16)vv[2]; s2 = cv.u;
            cv.b = (__bf16)vv[3]; s3 = cv.u;
            const int brow = mw * 16 + lk * 4;
            const char* hbp0 = (const char*)(hnxt + ((size_t)(l * B + brow)) * H + g);
            const char* hbp1 = hbp0 + 4096;   // rows +2, +3 (offset field is 13-bit signed)
            asm volatile(
                "global_store_short %[a0], %[v0], off sc0 sc1\n\t"
                "global_store_short %[a0], %[v1], off offset:2048 sc0 sc1\n\t"
                "global_store_short %[a1], %[v2], off sc0 sc1\n\t"
                "global_store_short %[a1], %[v3], off offset:2048 sc0 sc1"
                :: [a0]"v"(hbp0), [a1]"v"(hbp1),
                   [v0]"v"(s0), [v1]"v"(s1), [v2]"v"(s2), [v3]"v"(s3)
                : "memory");
            #pragma unroll
            for (int j = 0; j < 4; ++j) {
                int b = brow + j;
                if (l == L - 1) out[((size_t)b * T + t) * H + g] = vv[j];
                if (t == T - 1)
                    out[(size_t)B * T * H + ((size_t)(l * B + b)) * H + g] = vv[j];
            }
        }

        // ---- release: drain stores to IF, then relaxed signal --------------
        asm volatile("s_waitcnt vmcnt(0)" ::: "memory");
        __syncthreads();
        if (tid == 0)
            __hip_atomic_fetch_add(ctr, 1u, __ATOMIC_RELAXED,
                                   __HIP_MEMORY_SCOPE_AGENT);

        // ---- overlap: x-projection for t+1 (cached, no h dependence) -------
        if (t + 1 < T) {
            axA = zero; axB = zero;
            const __bf16* xb = xbf + (size_t)(t + 1) * B * IN;
            #pragma unroll
            for (int ck = 0; ck < 2; ++ck) {
                __syncthreads();
                STAGE_X(xb, ck * 256);
                __syncthreads();
                MFMA_CHUNK(ck * 256, axA, axB);
            }
        }
    }
}

// ---------------------------------------------------------------------------
extern "C" void kernel_launch(void* const* d_in, const int* in_sizes, int n_in,
                              void* d_out, int out_size, void* d_ws, size_t ws_size,
                              hipStream_t stream) {
    const float* x   = (const float*)d_in[0];
    const float* h0  = (const float*)d_in[1];
    const float* wih = (const float*)d_in[2];
    const float* whh = (const float*)d_in[3];
    const float* bih = (const float*)d_in[4];
    const float* bhh = (const float*)d_in[5];
    float* out = (float*)d_out;

    char* ws = (char*)d_ws;
    __bf16* xbf = (__bf16*)ws;                               // 16 MB
    __bf16* hb0 = (__bf16*)(ws + (size_t)16777216);          // 768 KB
    __bf16* hb1 = (__bf16*)(ws + (size_t)16777216 + 786432); // 768 KB
    unsigned* ctrs = (unsigned*)(ws + (size_t)16777216 + 2 * 786432);

    hipMemsetAsync(ctrs, 0, L * 16 * sizeof(unsigned), stream);
    prep_kernel<<<2048, 256, 0, stream>>>(x, h0, xbf, hb0);

    static bool attr_done = []() {
        hipFuncSetAttribute((const void*)rnn_kernel,
                            hipFuncAttributeMaxDynamicSharedMemorySize,
                            SMEM_BYTES);
        return true;
    }();
    (void)attr_done;

    rnn_kernel<<<NBLK, TPB, SMEM_BYTES, stream>>>(
        xbf, wih, whh, bih, bhh, hb0, hb1, out, ctrs);
}